// Round 9
// baseline (406.997 us; speedup 1.0000x reference)
//
#include <hip/hip_runtime.h>

#define NN 50000
#define NE 800000
#define NEG 0.2f

constexpr int NB1 = (NN + 255) / 256;   // 196 scan blocks

__device__ __forceinline__ float lrelu(float x) { return x > 0.f ? x : NEG * x; }

// ---------------- CSR build ----------------
__global__ void hist_k(const int* __restrict__ dst, int* __restrict__ deg) {
    int i = blockIdx.x * 256 + threadIdx.x;
    if (i < NE) atomicAdd(&deg[dst[i]], 1);
}

__global__ void scan1_k(const int* __restrict__ deg, int* __restrict__ roff,
                        int* __restrict__ bsum) {
    __shared__ int s[256];
    int t = threadIdx.x;
    int i = blockIdx.x * 256 + t;
    int v = (i < NN) ? deg[i] : 0;
    s[t] = v; __syncthreads();
    for (int off = 1; off < 256; off <<= 1) {
        int add = (t >= off) ? s[t - off] : 0;
        __syncthreads();
        s[t] += add;
        __syncthreads();
    }
    if (i < NN) roff[i] = s[t] - v;           // exclusive
    if (t == 255) bsum[blockIdx.x] = s[255];
}

__global__ void scan2_k(const int* __restrict__ bsum, int* __restrict__ boff,
                        int* __restrict__ roff) {
    __shared__ int s[256];
    int t = threadIdx.x;
    int v = (t < NB1) ? bsum[t] : 0;
    s[t] = v; __syncthreads();
    for (int off = 1; off < 256; off <<= 1) {
        int add = (t >= off) ? s[t - off] : 0;
        __syncthreads();
        s[t] += add;
        __syncthreads();
    }
    if (t < NB1) boff[t] = s[t] - v;
    if (t == 255) roff[NN] = s[255];          // total = NE
}

__global__ void scan3_k(int* __restrict__ roff, const int* __restrict__ boff,
                        int* __restrict__ cursor) {
    int i = blockIdx.x * 256 + threadIdx.x;
    if (i < NN) {
        int v = roff[i] + boff[blockIdx.x];
        roff[i] = v;
        cursor[i] = v;
    }
}

__global__ void fill_k(const int* __restrict__ src, const int* __restrict__ dst,
                       int* __restrict__ cursor, int* __restrict__ csr) {
    int i = blockIdx.x * 256 + threadIdx.x;
    if (i < NE) {
        int p = atomicAdd(&cursor[dst[i]], 1);
        csr[p] = src[i];
    }
}

// ---------------- fp32 GEMM [M,K]x[K,128] + fused attention logits ----------------
// A-tile stored k-major (sAT[kk][row]) so the inner loop reads the A fragment as
// two broadcast ds_read_b128 instead of 8 scalar ds_read_b32.
template <int K, int HEADS>
__global__ __launch_bounds__(256) void gemm_k(const float* __restrict__ A,
                                              const float* __restrict__ W,
                                              const float* __restrict__ att_s,
                                              const float* __restrict__ att_d,
                                              float* __restrict__ O,
                                              float* __restrict__ als,
                                              float* __restrict__ ald, int M) {
    __shared__ float sAT[32][68];    // k-major, row stride 272B (16B aligned)
    __shared__ float sB[32][128];
    int row0 = blockIdx.x * 64;
    int t = threadIdx.x;
    int rg = t >> 5;      // 0..7 -> rows rg*8 .. rg*8+7
    int cg = t & 31;      // 0..31 -> cols cg*4 .. cg*4+3
    float acc[8][4] = {};
    for (int k0 = 0; k0 < K; k0 += 32) {
        #pragma unroll
        for (int p = 0; p < 2; ++p) {
            int r = p * 32 + (t >> 3);          // 0..63
            int kk4 = (t & 7) * 4;              // 0,4,..,28
            int gr = row0 + r;
            float4 v = make_float4(0.f, 0.f, 0.f, 0.f);
            if (gr < M) v = *reinterpret_cast<const float4*>(&A[(size_t)gr * K + k0 + kk4]);
            sAT[kk4 + 0][r] = v.x;
            sAT[kk4 + 1][r] = v.y;
            sAT[kk4 + 2][r] = v.z;
            sAT[kk4 + 3][r] = v.w;
        }
        #pragma unroll
        for (int p = 0; p < 4; ++p) {
            int kr = p * 8 + (t >> 5);
            int c4 = (t & 31) * 4;
            *reinterpret_cast<float4*>(&sB[kr][c4]) =
                *reinterpret_cast<const float4*>(&W[(size_t)(k0 + kr) * 128 + c4]);
        }
        __syncthreads();
        #pragma unroll
        for (int kk = 0; kk < 32; ++kk) {
            float4 a0 = *reinterpret_cast<const float4*>(&sAT[kk][rg * 8]);
            float4 a1 = *reinterpret_cast<const float4*>(&sAT[kk][rg * 8 + 4]);
            float4 bv = *reinterpret_cast<const float4*>(&sB[kk][cg * 4]);
            float ar[8] = {a0.x, a0.y, a0.z, a0.w, a1.x, a1.y, a1.z, a1.w};
            #pragma unroll
            for (int r = 0; r < 8; ++r) {
                acc[r][0] += ar[r] * bv.x;
                acc[r][1] += ar[r] * bv.y;
                acc[r][2] += ar[r] * bv.z;
                acc[r][3] += ar[r] * bv.w;
            }
        }
        __syncthreads();
    }
    // epilogue: store O rows + fused attention logits
    constexpr int GROUP = 32 / HEADS;            // lanes per head-reduction (8 or 32)
    float4 as4 = *reinterpret_cast<const float4*>(&att_s[cg * 4]);
    float4 ad4 = *reinterpret_cast<const float4*>(&att_d[cg * 4]);
    #pragma unroll
    for (int r = 0; r < 8; ++r) {
        int gr = row0 + rg * 8 + r;
        float4 o = make_float4(acc[r][0], acc[r][1], acc[r][2], acc[r][3]);
        float ps = o.x * as4.x + o.y * as4.y + o.z * as4.z + o.w * as4.w;
        float pd = o.x * ad4.x + o.y * ad4.y + o.z * ad4.z + o.w * ad4.w;
        #pragma unroll
        for (int m = 1; m < GROUP; m <<= 1) {    // stays within the 32-lane half
            ps += __shfl_xor(ps, m, 64);
            pd += __shfl_xor(pd, m, 64);
        }
        if (gr < M) {
            *reinterpret_cast<float4*>(&O[(size_t)gr * 128 + cg * 4]) = o;
            if ((cg & (GROUP - 1)) == 0) {
                int h = cg / GROUP;
                als[(size_t)gr * HEADS + h] = ps;
                ald[(size_t)gr * HEADS + h] = pd;
            }
        }
    }
}

// ---------------- aggregate, layer 1 (4 heads x 32ch) -> elu(agg + b1) ----------------
// One wave per node; half-wave per edge, 2-wide unrolled (4 edges in flight per wave).
// No segment-max: softmax is shift-invariant and logits are bounded (|e| << 88),
// so exp() cannot overflow; matches reference to fp32 rounding.
__global__ __launch_bounds__(256) void agg1_k(const int* __restrict__ roff,
                                              const int* __restrict__ csr,
                                              const float* __restrict__ xp,
                                              const float* __restrict__ als,
                                              const float* __restrict__ ald,
                                              const float* __restrict__ b,
                                              float* __restrict__ hout) {
    int node = (blockIdx.x * 256 + threadIdx.x) >> 6;
    int lane = threadIdx.x & 63;
    if (node >= NN) return;
    int hw = lane >> 5;        // half-wave index (edge parity)
    int l  = lane & 31;        // feature group: ch 4l..4l+3
    int h  = l >> 3;           // head of this lane's features
    int e0 = roff[node], e1 = roff[node + 1];

    float4 adv = *reinterpret_cast<const float4*>(&ald[node * 4]);
    float4 sv  = *reinterpret_cast<const float4*>(&als[node * 4]);
    float adh = (h == 0) ? adv.x : (h == 1) ? adv.y : (h == 2) ? adv.z : adv.w;
    float svh = (h == 0) ? sv.x  : (h == 1) ? sv.y  : (h == 2) ? sv.z  : sv.w;

    // two independent accumulator sets (edges j and j+2 per iteration)
    float aA0 = 0.f, aA1 = 0.f, aA2 = 0.f, aA3 = 0.f, zA = 0.f;
    float aB0 = 0.f, aB1 = 0.f, aB2 = 0.f, aB3 = 0.f, zB = 0.f;
    if (hw == 0) {   // self loop on half 0, set A
        float ex = __expf(lrelu(svh + adh));
        zA = ex;
        float4 v = *reinterpret_cast<const float4*>(&xp[(size_t)node * 128 + 4 * l]);
        aA0 = ex * v.x; aA1 = ex * v.y; aA2 = ex * v.z; aA3 = ex * v.w;
    }
    for (int j = e0 + hw; j < e1; j += 4) {
        int sA = csr[j];
        int jB = j + 2;
        bool hasB = jB < e1;
        int sB = hasB ? csr[jB] : sA;          // aliased-safe when no B edge
        // broadcast float4 row load (one 16B probe per half-wave) + register select
        float4 avA = *reinterpret_cast<const float4*>(&als[sA * 4]);
        float4 avB = *reinterpret_cast<const float4*>(&als[sB * 4]);
        float alA = (h == 0) ? avA.x : (h == 1) ? avA.y : (h == 2) ? avA.z : avA.w;
        float alB = (h == 0) ? avB.x : (h == 1) ? avB.y : (h == 2) ? avB.z : avB.w;
        float exA = __expf(lrelu(alA + adh));
        float exB = hasB ? __expf(lrelu(alB + adh)) : 0.f;
        float4 vA = *reinterpret_cast<const float4*>(&xp[(size_t)sA * 128 + 4 * l]);
        float4 vB = *reinterpret_cast<const float4*>(&xp[(size_t)sB * 128 + 4 * l]);
        zA += exA; aA0 += exA * vA.x; aA1 += exA * vA.y; aA2 += exA * vA.z; aA3 += exA * vA.w;
        zB += exB; aB0 += exB * vB.x; aB1 += exB * vB.y; aB2 += exB * vB.z; aB3 += exB * vB.w;
    }
    float a0 = aA0 + aB0, a1 = aA1 + aB1, a2 = aA2 + aB2, a3 = aA3 + aB3, z = zA + zB;
    // merge halves
    a0 += __shfl_xor(a0, 32, 64);
    a1 += __shfl_xor(a1, 32, 64);
    a2 += __shfl_xor(a2, 32, 64);
    a3 += __shfl_xor(a3, 32, 64);
    z  += __shfl_xor(z, 32, 64);
    if (hw == 0) {
        float inv = 1.f / (z + 1e-16f);
        float4 bb = *reinterpret_cast<const float4*>(&b[4 * l]);
        float o0 = a0 * inv + bb.x, o1 = a1 * inv + bb.y;
        float o2 = a2 * inv + bb.z, o3 = a3 * inv + bb.w;
        o0 = o0 > 0.f ? o0 : expm1f(o0);
        o1 = o1 > 0.f ? o1 : expm1f(o1);
        o2 = o2 > 0.f ? o2 : expm1f(o2);
        o3 = o3 > 0.f ? o3 : expm1f(o3);
        *reinterpret_cast<float4*>(&hout[(size_t)node * 128 + 4 * l]) =
            make_float4(o0, o1, o2, o3);
    }
}

// ---------------- aggregate, layer 2 (1 head x 128ch) -> agg + b2 ----------------
__global__ __launch_bounds__(256) void agg2_k(const int* __restrict__ roff,
                                              const int* __restrict__ csr,
                                              const float* __restrict__ xp,
                                              const float* __restrict__ als,
                                              const float* __restrict__ ald,
                                              const float* __restrict__ b,
                                              float* __restrict__ out) {
    int node = (blockIdx.x * 256 + threadIdx.x) >> 6;
    int lane = threadIdx.x & 63;
    if (node >= NN) return;
    int hw = lane >> 5;
    int l  = lane & 31;
    int e0 = roff[node], e1 = roff[node + 1];
    float ad = ald[node];
    float sl = als[node];

    float aA0 = 0.f, aA1 = 0.f, aA2 = 0.f, aA3 = 0.f, zA = 0.f;
    float aB0 = 0.f, aB1 = 0.f, aB2 = 0.f, aB3 = 0.f, zB = 0.f;
    if (hw == 0) {
        float ex = __expf(lrelu(sl + ad));
        zA = ex;
        float4 v = *reinterpret_cast<const float4*>(&xp[(size_t)node * 128 + 4 * l]);
        aA0 = ex * v.x; aA1 = ex * v.y; aA2 = ex * v.z; aA3 = ex * v.w;
    }
    for (int j = e0 + hw; j < e1; j += 4) {
        int sA = csr[j];
        int jB = j + 2;
        bool hasB = jB < e1;
        int sB = hasB ? csr[jB] : sA;
        float alA = als[sA];
        float alB = als[sB];
        float exA = __expf(lrelu(alA + ad));
        float exB = hasB ? __expf(lrelu(alB + ad)) : 0.f;
        float4 vA = *reinterpret_cast<const float4*>(&xp[(size_t)sA * 128 + 4 * l]);
        float4 vB = *reinterpret_cast<const float4*>(&xp[(size_t)sB * 128 + 4 * l]);
        zA += exA; aA0 += exA * vA.x; aA1 += exA * vA.y; aA2 += exA * vA.z; aA3 += exA * vA.w;
        zB += exB; aB0 += exB * vB.x; aB1 += exB * vB.y; aB2 += exB * vB.z; aB3 += exB * vB.w;
    }
    float a0 = aA0 + aB0, a1 = aA1 + aB1, a2 = aA2 + aB2, a3 = aA3 + aB3, z = zA + zB;
    a0 += __shfl_xor(a0, 32, 64);
    a1 += __shfl_xor(a1, 32, 64);
    a2 += __shfl_xor(a2, 32, 64);
    a3 += __shfl_xor(a3, 32, 64);
    z  += __shfl_xor(z, 32, 64);
    if (hw == 0) {
        float inv = 1.f / (z + 1e-16f);
        float4 bb = *reinterpret_cast<const float4*>(&b[4 * l]);
        *reinterpret_cast<float4*>(&out[(size_t)node * 128 + 4 * l]) =
            make_float4(a0 * inv + bb.x, a1 * inv + bb.y, a2 * inv + bb.z, a3 * inv + bb.w);
    }
}

extern "C" void kernel_launch(void* const* d_in, const int* in_sizes, int n_in,
                              void* d_out, int out_size, void* d_ws, size_t ws_size,
                              hipStream_t stream) {
    const float* x   = (const float*)d_in[0];
    const int*   src = (const int*)d_in[1];
    const int*   dst = (const int*)d_in[2];
    const float* W1  = (const float*)d_in[3];
    const float* as1 = (const float*)d_in[4];
    const float* ad1 = (const float*)d_in[5];
    const float* b1  = (const float*)d_in[6];
    const float* W2  = (const float*)d_in[7];
    const float* as2 = (const float*)d_in[8];
    const float* ad2 = (const float*)d_in[9];
    const float* b2  = (const float*)d_in[10];
    float* out = (float*)d_out;

    char* ws = (char*)d_ws;
    size_t off = 0;
    auto alloc = [&](size_t bytes) {
        size_t o = off;
        off = (off + bytes + 255) & ~(size_t)255;
        return o;
    };
    int*   roff   = (int*)(ws + alloc((NN + 1) * 4));
    int*   cursor = (int*)(ws + alloc(NN * 4));
    int*   deg    = (int*)(ws + alloc(NN * 4));
    int*   bsum   = (int*)(ws + alloc(256 * 4));
    int*   boff   = (int*)(ws + alloc(256 * 4));
    int*   csr    = (int*)(ws + alloc((size_t)NE * 4));
    float* xp1    = (float*)(ws + alloc((size_t)NN * 128 * 4));   // reused as xp2
    float* als1   = (float*)(ws + alloc((size_t)NN * 4 * 4));     // reused as als2
    float* ald1   = (float*)(ws + alloc((size_t)NN * 4 * 4));     // reused as ald2
    float* hbuf   = (float*)(ws + alloc((size_t)NN * 128 * 4));
    // layer-2 aliases (xp1/als1/ald1 are dead after agg1_k)
    float* xp2  = xp1;
    float* als2 = als1;
    float* ald2 = ald1;

    // ---- CSR build (shared by both layers) ----
    hipMemsetAsync(deg, 0, (size_t)NN * 4, stream);
    hist_k<<<(NE + 255) / 256, 256, 0, stream>>>(dst, deg);
    scan1_k<<<NB1, 256, 0, stream>>>(deg, roff, bsum);
    scan2_k<<<1, 256, 0, stream>>>(bsum, boff, roff);
    scan3_k<<<NB1, 256, 0, stream>>>(roff, boff, cursor);
    fill_k<<<(NE + 255) / 256, 256, 0, stream>>>(src, dst, cursor, csr);

    int aggGrid  = (NN + 3) / 4;      // 4 waves (nodes) per 256-thread block
    int gemmGrid = (NN + 63) / 64;

    // ---- layer 1: gemm(+logits) -> aggregate ----
    gemm_k<256, 4><<<gemmGrid, 256, 0, stream>>>(x, W1, as1, ad1, xp1, als1, ald1, NN);
    agg1_k<<<aggGrid, 256, 0, stream>>>(roff, csr, xp1, als1, ald1, b1, hbuf);

    // ---- layer 2: gemm(+logits) -> aggregate ----
    gemm_k<128, 1><<<gemmGrid, 256, 0, stream>>>(hbuf, W2, as2, ad2, xp2, als2, ald2, NN);
    agg2_k<<<aggGrid, 256, 0, stream>>>(roff, csr, xp2, als2, ald2, b2, out);
}